// Round 1
// baseline (64929.016 us; speedup 1.0000x reference)
//
#include <hip/hip_runtime.h>
#include <stdint.h>
#include <math.h>

#define BB 128
#define TT 19
#define MF_N 1024
#define GC_N 2048
#define PC_N 1024
#define DCN_N 1408
#define GC_K 1024
#define PC_K 8192
#define DCN_K 2048
#define STEPS 361   // 19 outer * 19 inner, state carried through

using i32x4 = __attribute__((ext_vector_type(4))) int;

// ---------------- persistent state / precomputed data (module globals) ------
__device__ double g_memMF[4L*BB*MF_N];
__device__ double g_memGC[4L*BB*GC_N];
__device__ double g_memPC[2L*BB*PC_N];
__device__ double g_memDCN[(long)BB*DCN_N];
__device__ __align__(16) signed char g_sMF[4L*BB*MF_N];   // i8 spikes stacked (512,1024)
__device__ __align__(16) signed char g_sGC[4L*BB*GC_N];   // stacked (512,2048) == PF_in
__device__ __align__(16) signed char g_sPC[2L*BB*PC_N];   // stacked (256,1024) == DCN_in
__device__ __align__(16) signed char g_plGC[4L*4*GC_N*GC_K];
__device__ __align__(16) signed char g_plPC[2L*4*PC_N*PC_K];
__device__ __align__(16) signed char g_plDCN[4L*DCN_N*DCN_K];
__device__ double g_preMF[4L*TT*BB*MF_N];     // precomputed x_t @ W^T (fp64)
__device__ double g_partPC[2L*4*BB*PC_N];     // [path][ksp=4][m][n] integer-valued fp64
__device__ double g_partDCN[4L*BB*DCN_N];     // [ksp=4][m*1408+n]
__device__ double g_rowsum[DCN_N];
__device__ int g_cnt[STEPS];
__device__ int g_outacc[(long)BB*DCN_N];

// persistent-kernel synchronization state (reset every graph replay by init_state)
__device__ int g_barLeaf[32*16];   // 32 leaves, padded to 64B
__device__ int g_barRoot;
__device__ int g_release;
__device__ int g_pcArr[64];        // per (path,nt) K-split completion counters
__device__ int g_dcnArr[44];       // per nt K-split completion counters

__global__ void init_state()
{
    long i = (long)blockIdx.x * 256 + threadIdx.x;
    if (i < 4L*BB*MF_N) g_memMF[i] = 0.0;
    if (i < 4L*BB*GC_N) g_memGC[i] = 0.0;
    if (i < 2L*BB*PC_N) g_memPC[i] = 0.0;
    if (i < (long)BB*DCN_N) { g_memDCN[i] = 0.0; g_outacc[i] = 0; }
    if (i < STEPS) g_cnt[i] = 0;
    if (i < 32*16) g_barLeaf[i] = 0;
    if (i < 64) g_pcArr[i] = 0;
    if (i < 44) g_dcnArr[i] = 0;
    if (i == 0) { g_barRoot = 0; g_release = 0; }
}

// Decompose fp32 weights into 4 signed-i8 digit planes of llrint(w * S) (exact).
__global__ void decompose(const float* W, int which, double S)
{
    signed char* dst; long NK;
    if (which < 4)      { dst = g_plGC + (long)which*4*GC_N*GC_K; NK = (long)GC_N*GC_K; }
    else if (which < 6) { dst = g_plPC + (long)(which-4)*4*PC_N*PC_K; NK = (long)PC_N*PC_K; }
    else                { dst = g_plDCN; NK = (long)DCN_N*DCN_K; }
    for (long i = (long)blockIdx.x*256 + threadIdx.x; i < NK; i += 4096L*256) {
        long long v = llrint((double)W[i] * S);
        #pragma unroll
        for (int p = 0; p < 3; ++p) {
            signed char d = (signed char)(v & 0xFF);
            dst[(long)p*NK + i] = d;
            v = (v - d) >> 8;
        }
        dst[3L*NK + i] = (signed char)v;
    }
}

__global__ void rowsum_f64(const float* Wd)
{
    const int n = blockIdx.x * 256 + threadIdx.x;
    if (n < DCN_N) {
        double s = 0.0;
        const float* row = Wd + (long)n * DCN_K;
        for (int k = 0; k < DCN_K; ++k) s += (double)row[k];
        g_rowsum[n] = s;
    }
}

// ---------------- one-time fp64 GEMM: pre[path][t] = x_t @ W^T --------------
struct PreArgs { const float* X[4]; const float* W[4]; int K[4]; };

__global__ __launch_bounds__(256) void pre_gemm(PreArgs pa)
{
    const int z = blockIdx.z;
    const int path = z / TT, t = z % TT;
    const int K = pa.K[path];
    const float* A = pa.X[path] + (long)t * K;
    const long astride = 19L * K;
    const float* W = pa.W[path];
    const int tid = threadIdx.x;
    const int m0 = blockIdx.x * 64, n0 = blockIdx.y * 64;
    const int tx = tid & 15, ty = tid >> 4;

    __shared__ double Al[32][65];
    __shared__ double Bl[32][65];

    double acc[4][4];
    #pragma unroll
    for (int i = 0; i < 4; ++i)
        #pragma unroll
        for (int j = 0; j < 4; ++j) acc[i][j] = 0.0;

    const int am = tid & 63, akg = (tid >> 6) * 8;
    const float* asrc = A + (long)(m0 + am) * astride + akg;
    const float* bsrc = W + (long)(n0 + am) * K + akg;

    for (int k0 = 0; k0 < K; k0 += 32) {
        __syncthreads();
        {
            float4 v0 = *(const float4*)(asrc + k0);
            float4 v1 = *(const float4*)(asrc + k0 + 4);
            Al[akg+0][am]=(double)v0.x; Al[akg+1][am]=(double)v0.y;
            Al[akg+2][am]=(double)v0.z; Al[akg+3][am]=(double)v0.w;
            Al[akg+4][am]=(double)v1.x; Al[akg+5][am]=(double)v1.y;
            Al[akg+6][am]=(double)v1.z; Al[akg+7][am]=(double)v1.w;
        }
        {
            float4 v0 = *(const float4*)(bsrc + k0);
            float4 v1 = *(const float4*)(bsrc + k0 + 4);
            Bl[akg+0][am]=(double)v0.x; Bl[akg+1][am]=(double)v0.y;
            Bl[akg+2][am]=(double)v0.z; Bl[akg+3][am]=(double)v0.w;
            Bl[akg+4][am]=(double)v1.x; Bl[akg+5][am]=(double)v1.y;
            Bl[akg+6][am]=(double)v1.z; Bl[akg+7][am]=(double)v1.w;
        }
        __syncthreads();

        #pragma unroll 8
        for (int k = 0; k < 32; ++k) {
            const double a0 = Al[k][ty*4+0], a1 = Al[k][ty*4+1],
                         a2 = Al[k][ty*4+2], a3 = Al[k][ty*4+3];
            const double b0 = Bl[k][tx*4+0], b1 = Bl[k][tx*4+1],
                         b2 = Bl[k][tx*4+2], b3 = Bl[k][tx*4+3];
            acc[0][0]=fma(a0,b0,acc[0][0]); acc[0][1]=fma(a0,b1,acc[0][1]);
            acc[0][2]=fma(a0,b2,acc[0][2]); acc[0][3]=fma(a0,b3,acc[0][3]);
            acc[1][0]=fma(a1,b0,acc[1][0]); acc[1][1]=fma(a1,b1,acc[1][1]);
            acc[1][2]=fma(a1,b2,acc[1][2]); acc[1][3]=fma(a1,b3,acc[1][3]);
            acc[2][0]=fma(a2,b0,acc[2][0]); acc[2][1]=fma(a2,b1,acc[2][1]);
            acc[2][2]=fma(a2,b2,acc[2][2]); acc[2][3]=fma(a2,b3,acc[2][3]);
            acc[3][0]=fma(a3,b0,acc[3][0]); acc[3][1]=fma(a3,b1,acc[3][1]);
            acc[3][2]=fma(a3,b2,acc[3][2]); acc[3][3]=fma(a3,b3,acc[3][3]);
        }
    }

    double* out = g_preMF + (long)(path*TT + t) * BB * MF_N;
    #pragma unroll
    for (int i = 0; i < 4; ++i)
        #pragma unroll
        for (int j = 0; j < 4; ++j)
            __builtin_nontemporal_store(acc[i][j],
                &out[(long)(m0 + ty*4 + i) * MF_N + (n0 + tx*4 + j)]);
}

// ---------------- persistent megakernel ------------------------------------
struct LoopArgs {
    const float* bmf[4];
    const float* bgc[4];
    const float* bpcE;
    const float* bpcI;
    const float* bdcn;
};

// Two-level grid barrier. Safe because all 256 blocks are co-resident
// (256 blocks, __launch_bounds__(512,2) => block fits 1/CU on 256 CUs).
// ACQ_REL agent-scope RMWs give cross-XCD release (L2 writeback) on arrive
// and acquire (cache inv) on the final fence — same visibility a kernel
// boundary provided in the multi-launch version.
__device__ __forceinline__ void grid_barrier(const int bid, const int tid, const int bcnt)
{
    __syncthreads();
    if (tid == 0) {
        const int leaf = bid & 31;
        const int lp = __hip_atomic_fetch_add(&g_barLeaf[leaf*16], 1,
                           __ATOMIC_ACQ_REL, __HIP_MEMORY_SCOPE_AGENT);
        if (lp == 8*bcnt + 7) {
            const int rp = __hip_atomic_fetch_add(&g_barRoot, 1,
                               __ATOMIC_ACQ_REL, __HIP_MEMORY_SCOPE_AGENT);
            if (rp == 32*bcnt + 31)
                __hip_atomic_store(&g_release, bcnt + 1,
                                   __ATOMIC_RELEASE, __HIP_MEMORY_SCOPE_AGENT);
        }
        while (__hip_atomic_load(&g_release, __ATOMIC_RELAXED,
                                 __HIP_MEMORY_SCOPE_AGENT) < bcnt + 1)
            __builtin_amdgcn_s_sleep(2);
        __builtin_amdgcn_fence(__ATOMIC_ACQUIRE, "agent");
    }
    __syncthreads();
}

__device__ __forceinline__ void mf_phase(const int bid, const int tid, const int s,
                                         const LoopArgs& la, int* bc)
{
    const int t = s % TT;
    if (tid == 0) *bc = 0;
    __syncthreads();
    int lc = 0;
    #pragma unroll
    for (int path = 0; path < 4; ++path) {
        const long rc = (long)bid*512 + tid;            // 0..131071
        const long i = (long)path*131072 + rc;
        const int col = (int)(rc & 1023);
        const double mo = g_memMF[i];
        const double dec = (mo > 0.5) ? 0.0 : mo * 0.2;
        const double pre = __builtin_nontemporal_load(
            &g_preMF[(long)(path*TT + t)*BB*MF_N + rc]);
        const double mn = (dec + pre) + (double)la.bmf[path][col];
        g_memMF[i] = mn;
        const bool sp = mn > 0.5;
        g_sMF[i] = sp ? 1 : 0;
        unsigned long long bal = __ballot(sp);
        if ((tid & 63) == 0) lc += (int)__popcll(bal);
    }
    if ((tid & 63) == 0 && lc) atomicAdd(bc, lc);
    __syncthreads();
    if (tid == 0 && *bc) atomicAdd(&g_cnt[s], *bc);
}

// Spike GEMM phase. LAYER 1=GC (fused epilogue), 2=PC (+fused pc_fin via
// per-tile sub-barrier), 3=DCN (+fused DCN finish via sub-barrier).
template<int LAYER>
__device__ __forceinline__ void gemm_phase(const int bid, const int tid, const int step,
                                           const LoopArgs& la, signed char* ldsraw, int* shflag)
{
    constexpr int N   = (LAYER==1) ? GC_N : (LAYER==2) ? PC_N : DCN_N;
    constexpr int K   = (LAYER==1) ? GC_K : (LAYER==2) ? PC_K : DCN_K;
    constexpr int KCH = (LAYER==1) ? GC_K : (LAYER==2) ? PC_K/4 : DCN_K/4;
    constexpr long NK = (long)N * K;
    constexpr int NST = KCH / 128;

    if constexpr (LAYER == 3) { if (bid >= 176) return; }

    int nt, ksp, path;
    if constexpr (LAYER == 1)      { nt = bid & 63; ksp = 0;              path = bid >> 6; }
    else if constexpr (LAYER == 2) { nt = bid & 31; ksp = (bid >> 5) & 3; path = bid >> 7; }
    else                           { nt = bid % 44; ksp = bid / 44;       path = 0; }

    const int wave = tid >> 6, lane = tid & 63, l16 = lane & 15, quad = lane >> 4;
    const int mg = wave >> 1, ng = wave & 1;
    const int n0 = nt * 32;
    const int k0 = ksp * KCH;

    const signed char* A; const signed char* pl;
    if constexpr (LAYER == 1)      { A = g_sMF + (long)path*BB*GC_K; pl = g_plGC + (long)path*4*NK; }
    else if constexpr (LAYER == 2) { A = g_sGC;                      pl = g_plPC + (long)path*4*NK; }
    else                           { A = g_sPC;                      pl = g_plDCN; }

    auto Bls = (signed char (*)[4][32][144])ldsraw;

    i32x4 acc[2][4];
    #pragma unroll
    for (int m = 0; m < 2; ++m)
        #pragma unroll
        for (int p = 0; p < 4; ++p) acc[m][p] = (i32x4){0,0,0,0};

    const int c0 = tid, c1 = tid + 512;
    const int p0 = c0 >> 8, n0c = (c0 >> 3) & 31, k0c = c0 & 7;
    const int p1 = c1 >> 8, n1c = (c1 >> 3) & 31, k1c = c1 & 7;
    const signed char* gb0 = pl + (long)p0*NK + (long)(n0 + n0c)*K + k0 + k0c*16;
    const signed char* gb1 = pl + (long)p1*NK + (long)(n0 + n1c)*K + k0 + k1c*16;

    i32x4 ld0, ld1;
    auto stage_regs = [&](int st) {
        ld0 = *(const i32x4*)(gb0 + st*128);
        ld1 = *(const i32x4*)(gb1 + st*128);
    };
    auto write_lds = [&](int buf) {
        *(i32x4*)(&Bls[buf][p0][n0c][k0c*16]) = ld0;
        *(i32x4*)(&Bls[buf][p1][n1c][k1c*16]) = ld1;
    };

    const signed char* arow0 = A + (long)(mg*32 + l16)*K + k0 + quad*16;
    const signed char* arow1 = arow0 + 16L*K;
    const signed char* bbase = &Bls[0][0][ng*16 + l16][quad*16];

    stage_regs(0);
    write_lds(0);
    int buf = 0;
    for (int st = 0; st < NST; ++st) {
        __syncthreads();
        if (st + 1 < NST) stage_regs(st + 1);
        #pragma unroll
        for (int kk = 0; kk < 2; ++kk) {
            const int ka = st*128 + kk*64;
            i32x4 a0 = *(const i32x4*)(arow0 + ka);
            i32x4 a1 = *(const i32x4*)(arow1 + ka);
            #pragma unroll
            for (int p = 0; p < 4; ++p) {
                i32x4 b = *(const i32x4*)(bbase + (long)buf*4*32*144 + (long)p*32*144 + kk*64);
                acc[0][p] = __builtin_amdgcn_mfma_i32_16x16x64_i8(a0, b, acc[0][p], 0, 0, 0);
                acc[1][p] = __builtin_amdgcn_mfma_i32_16x16x64_i8(a1, b, acc[1][p], 0, 0, 0);
            }
        }
        if (st + 1 < NST) write_lds(buf ^ 1);
        buf ^= 1;
    }

    const int colg = n0 + ng*16 + l16;

    if constexpr (LAYER == 1) {
        double* mem = g_memGC + (long)path*BB*GC_N;
        signed char* spk = g_sGC + (long)path*BB*GC_N;
        const double bv = (double)la.bgc[path][colg];
        #pragma unroll
        for (int mt = 0; mt < 2; ++mt) {
            #pragma unroll
            for (int r = 0; r < 4; ++r) {
                const int row = mg*32 + mt*16 + quad*4 + r;
                double v = (double)acc[mt][3][r];
                v = v*256.0 + (double)acc[mt][2][r];
                v = v*256.0 + (double)acc[mt][1][r];
                v = v*256.0 + (double)acc[mt][0][r];
                v *= 0x1p-27;
                const long idx = (long)row*GC_N + colg;
                const double mo = mem[idx];
                const double dec = (mo > 0.5) ? 0.0 : mo * 0.2;
                const double mn = (dec + v) + bv;
                mem[idx] = mn;
                spk[idx] = (mn > 0.5) ? 1 : 0;
            }
        }
    } else if constexpr (LAYER == 2) {
        #pragma unroll
        for (int mt = 0; mt < 2; ++mt) {
            #pragma unroll
            for (int r = 0; r < 4; ++r) {
                const int row = mg*32 + mt*16 + quad*4 + r;
                double v = (double)acc[mt][3][r];
                v = v*256.0 + (double)acc[mt][2][r];
                v = v*256.0 + (double)acc[mt][1][r];
                v = v*256.0 + (double)acc[mt][0][r];
                g_partPC[((long)path*4 + ksp)*131072 + (long)row*PC_N + colg] = v;
            }
        }
        __syncthreads();
        if (tid == 0) {
            const int prev = __hip_atomic_fetch_add(&g_pcArr[path*32 + nt], 1,
                                 __ATOMIC_ACQ_REL, __HIP_MEMORY_SCOPE_AGENT);
            *shflag = (prev == 4*step + 3) ? 1 : 0;
        }
        __syncthreads();
        if (*shflag) {   // last K-split block of this (path,nt) finishes the tile
            #pragma unroll
            for (int j = 0; j < 8; ++j) {
                const int idx = tid + j*512;             // 0..4095 = 128 rows x 32 cols
                const int row = idx >> 5;
                const int col = n0 + (idx & 31);
                const long mn_idx = (long)row*PC_N + col;
                const double* pp = g_partPC + (long)path*4*131072 + mn_idx;
                double v = pp[0] + pp[131072] + pp[2*131072] + pp[3*131072];
                v *= 0x1p-30;
                const long tix = (long)path*131072 + mn_idx;
                const double mo = g_memPC[tix];
                const double dec = (mo > 0.5) ? 0.0 : mo * 0.2;
                const double mn = (dec + v) + (double)(path ? la.bpcI[col] : la.bpcE[col]);
                g_memPC[tix] = mn;
                g_sPC[tix] = (mn > 0.5) ? 1 : 0;
            }
        }
    } else {
        #pragma unroll
        for (int mt = 0; mt < 2; ++mt) {
            #pragma unroll
            for (int r = 0; r < 4; ++r) {
                const int row = mg*32 + mt*16 + quad*4 + r;
                double v = (double)acc[mt][3][r];
                v = v*256.0 + (double)acc[mt][2][r];
                v = v*256.0 + (double)acc[mt][1][r];
                v = v*256.0 + (double)acc[mt][0][r];
                g_partDCN[(long)ksp*180224 + (long)row*DCN_N + colg] = v;
            }
        }
        __syncthreads();
        if (tid == 0) {
            const int prev = __hip_atomic_fetch_add(&g_dcnArr[nt], 1,
                                 __ATOMIC_ACQ_REL, __HIP_MEMORY_SCOPE_AGENT);
            *shflag = (prev == 4*step + 3) ? 1 : 0;
        }
        __syncthreads();
        if (*shflag) {   // last K-split block of this nt finishes the tile
            const double basev = (double)g_cnt[step] * (1.0 / 524288.0) + 0.3;
            const int doacc = (step >= STEPS - TT) ? 1 : 0;
            #pragma unroll
            for (int j = 0; j < 8; ++j) {
                const int idx = tid + j*512;             // 0..4095
                const int row = idx >> 5;
                const int col = n0 + (idx & 31);
                const long jj = (long)row*DCN_N + col;
                double v = g_partDCN[jj] + g_partDCN[jj + 180224]
                         + g_partDCN[jj + 2*180224] + g_partDCN[jj + 3*180224];
                v = v * 0x1p-29 + basev * g_rowsum[col];
                const double mo = g_memDCN[jj];
                const double dec = (mo > 0.5) ? 0.0 : mo * 0.2;
                const double mn = (dec + v) + (double)la.bdcn[col];
                g_memDCN[jj] = mn;
                if (doacc && mn > 0.5) g_outacc[jj] += 1;
            }
        }
    }
}

__global__ __launch_bounds__(512, 2) void mega(LoopArgs la)
{
    const int bid = blockIdx.x;
    const int tid = threadIdx.x;
    __shared__ __align__(16) signed char ldsraw[2*4*32*144];
    __shared__ int sh_flag;
    __shared__ int sh_bc;

    int bcnt = 0;
    for (int s = 0; s < STEPS; ++s) {
        // phase 1: MF membranes + spike count
        mf_phase(bid, tid, s, la, &sh_bc);
        grid_barrier(bid, tid, bcnt); ++bcnt;
        // phase 2: GC gemm + fused membrane epilogue
        gemm_phase<1>(bid, tid, s, la, ldsraw, &sh_flag);
        grid_barrier(bid, tid, bcnt); ++bcnt;
        // phase 3: PC gemm + per-tile finisher (sub-barrier)
        gemm_phase<2>(bid, tid, s, la, ldsraw, &sh_flag);
        grid_barrier(bid, tid, bcnt); ++bcnt;
        // phase 4: DCN gemm + per-tile finisher; no barrier needed — phase 1 of
        // the next step touches disjoint state, and the next grid barrier
        // transitively covers phase-4 stragglers.
        gemm_phase<3>(bid, tid, s, la, ldsraw, &sh_flag);
    }
}

__global__ void write_out(float* out)
{
    const long i = (long)blockIdx.x * 256 + threadIdx.x;
    if (i < (long)BB * DCN_N) out[i] = (float)g_outacc[i];
}

extern "C" void kernel_launch(void* const* d_in, const int* in_sizes, int n_in,
                              void* d_out, int out_size, void* d_ws, size_t ws_size,
                              hipStream_t stream)
{
    const float* in_m  = (const float*)d_in[0];
    const float* in_u  = (const float*)d_in[1];
    const float* in_s  = (const float*)d_in[2];
    const float* in_f  = (const float*)d_in[3];
    const float* Wm_MF = (const float*)d_in[4];
    const float* bm_MF = (const float*)d_in[5];
    const float* Wu_MF = (const float*)d_in[6];
    const float* bu_MF = (const float*)d_in[7];
    const float* Ws_MF = (const float*)d_in[8];
    const float* bs_MF = (const float*)d_in[9];
    const float* Wf_MF = (const float*)d_in[10];
    const float* bf_MF = (const float*)d_in[11];
    const float* Wm_GC = (const float*)d_in[12];
    const float* bm_GC = (const float*)d_in[13];
    const float* Wu_GC = (const float*)d_in[14];
    const float* bu_GC = (const float*)d_in[15];
    const float* Ws_GC = (const float*)d_in[16];
    const float* bs_GC = (const float*)d_in[17];
    const float* Wf_GC = (const float*)d_in[18];
    const float* bf_GC = (const float*)d_in[19];
    const float* W_PCE = (const float*)d_in[20];
    const float* b_PCE = (const float*)d_in[21];
    const float* W_PCI = (const float*)d_in[22];
    const float* b_PCI = (const float*)d_in[23];
    const float* W_DCN = (const float*)d_in[24];
    const float* b_DCN = (const float*)d_in[25];

    init_state<<<4096, 256, 0, stream>>>();
    decompose<<<4096, 256, 0, stream>>>(Wm_GC, 0, 0x1p27);
    decompose<<<4096, 256, 0, stream>>>(Wu_GC, 1, 0x1p27);
    decompose<<<4096, 256, 0, stream>>>(Ws_GC, 2, 0x1p27);
    decompose<<<4096, 256, 0, stream>>>(Wf_GC, 3, 0x1p27);
    decompose<<<4096, 256, 0, stream>>>(W_PCE, 4, 0x1p30);
    decompose<<<4096, 256, 0, stream>>>(W_PCI, 5, 0x1p30);
    decompose<<<4096, 256, 0, stream>>>(W_DCN, 6, 0x1p29);
    rowsum_f64<<<(DCN_N + 255) / 256, 256, 0, stream>>>(W_DCN);

    {
        PreArgs pa;
        pa.X[0] = in_m; pa.X[1] = in_u; pa.X[2] = in_s; pa.X[3] = in_f;
        pa.W[0] = Wm_MF; pa.W[1] = Wu_MF; pa.W[2] = Ws_MF; pa.W[3] = Wf_MF;
        pa.K[0] = 320; pa.K[1] = 384; pa.K[2] = 384; pa.K[3] = 384;
        pre_gemm<<<dim3(2, 16, 4 * TT), 256, 0, stream>>>(pa);
    }

    LoopArgs la;
    la.bmf[0] = bm_MF; la.bmf[1] = bu_MF; la.bmf[2] = bs_MF; la.bmf[3] = bf_MF;
    la.bgc[0] = bm_GC; la.bgc[1] = bu_GC; la.bgc[2] = bs_GC; la.bgc[3] = bf_GC;
    la.bpcE = b_PCE; la.bpcI = b_PCI; la.bdcn = b_DCN;

    mega<<<256, 512, 0, stream>>>(la);

    write_out<<<((BB * DCN_N) + 255) / 256, 256, 0, stream>>>((float*)d_out);
}